// Round 2
// baseline (19314.349 us; speedup 1.0000x reference)
//
#include <hip/hip_runtime.h>
#include <hip/hip_bf16.h>
#include <math.h>

// EABlock: ExternalAttention (BN1 -> 1x1 conv k -> softmax(spatial) -> head-sum
// normalize -> 1x1 conv v -> +x) followed by MLP (BN2 -> conv3x3 -> GELU ->
// conv3x3 -> +x2). All fp32.
//
// Shapes: B=32, C=128, IC=256, NH=8, H=W=64 (HW=4096), HID=512.
//
// Workspace strategy: the pipeline is per-sample independent, so we process
// the batch in chunks of `bc` samples, with bc chosen from the REAL ws_size
// at launch time (constant across calls -> graph-safe).
// Per chunk (floats):
//   consts : keff 32768 | biask 256 | inv2 128 | beta2 128   (~130 KB)
//   SM     : bc * HID*HW  (mid; first bc*IC*HW floats double as S -- S is
//            dead before conv1 writes mid, stream-ordered)
//   hsum   : bc * NH*HW
// x2 lives in d_out (gemm2 writes it, conv1 reads it, conv2 reads it as
// residual and overwrites in-place -- same-thread same-element, race-free).

#define Bn 32
#define Cn 128
#define ICn 256
#define NHn 8
#define HWn 4096
#define HIDn 512

// ---------------------------------------------------------------- prep ----
__global__ __launch_bounds__(256) void prep_kernel(
    const float* __restrict__ bn1_g, const float* __restrict__ bn1_b,
    const float* __restrict__ bn1_m, const float* __restrict__ bn1_v,
    const float* __restrict__ kmat,
    const float* __restrict__ bn2_g, const float* __restrict__ bn2_b,
    const float* __restrict__ bn2_m, const float* __restrict__ bn2_v,
    float* __restrict__ keff, float* __restrict__ biask,
    float* __restrict__ inv2, float* __restrict__ beta2) {
  __shared__ float sinv1[Cn], sbeta1[Cn];
  const int t = threadIdx.x;  // 256
  if (t < Cn) {
    float i1 = bn1_g[t] / sqrtf(bn1_v[t] + 1e-5f);
    sinv1[t] = i1;
    sbeta1[t] = bn1_b[t] - bn1_m[t] * i1;
    float i2 = bn2_g[t] / sqrtf(bn2_v[t] + 1e-6f);
    inv2[t] = i2;
    beta2[t] = bn2_b[t] - bn2_m[t] * i2;
  }
  __syncthreads();
  // t = output channel o in [0,256)
  float bk = 0.f;
  for (int c = 0; c < Cn; ++c) {
    float kv = kmat[t * Cn + c];
    keff[t * Cn + c] = kv * sinv1[c];
    bk += kv * sbeta1[c];
  }
  biask[t] = bk;
}

// ------------------------------------------------------------- gemm1 ------
// S[bz,o,p] = biask[o] + sum_c keff[o,c] * x[b0+bz,c,p]
// grid (32 ptiles, 4 otiles, bc), block 256. O_TILE=64, P_TILE=128.
__global__ __launch_bounds__(256) void gemm1_kernel(
    const float* __restrict__ x, const float* __restrict__ keff,
    const float* __restrict__ biask, float* __restrict__ S, int b0) {
  const int pq = threadIdx.x & 31;   // float4 index within P tile
  const int og = threadIdx.x >> 5;   // 8 groups x 8 o
  const int p0 = blockIdx.x * 128;
  const int o0 = blockIdx.y * 64;
  const int bz = blockIdx.z;
  const int bg = b0 + bz;
  __shared__ float sk[64][128];   // 32 KB
  __shared__ float sx[32][128];   // 16 KB
  for (int i = threadIdx.x; i < 64 * 32; i += 256) {
    int r = i >> 5, c4 = i & 31;
    ((float4*)sk[r])[c4] = ((const float4*)(keff + (size_t)(o0 + r) * Cn))[c4];
  }
  float4 acc[8];
#pragma unroll
  for (int j = 0; j < 8; ++j) acc[j] = make_float4(0.f, 0.f, 0.f, 0.f);
  for (int cc = 0; cc < Cn; cc += 32) {
    __syncthreads();  // first iter also publishes sk
    for (int i = threadIdx.x; i < 32 * 32; i += 256) {
      int r = i >> 5, c4 = i & 31;
      ((float4*)sx[r])[c4] =
          ((const float4*)(x + ((size_t)bg * Cn + cc + r) * HWn + p0))[c4];
    }
    __syncthreads();
    for (int c = 0; c < 32; ++c) {
      float4 xv = ((float4*)sx[c])[pq];
#pragma unroll
      for (int j = 0; j < 8; ++j) {
        float kv = sk[og * 8 + j][cc + c];
        acc[j].x += kv * xv.x; acc[j].y += kv * xv.y;
        acc[j].z += kv * xv.z; acc[j].w += kv * xv.w;
      }
    }
  }
#pragma unroll
  for (int j = 0; j < 8; ++j) {
    int o = o0 + og * 8 + j;
    float bk = biask[o];
    float4 r = acc[j];
    r.x += bk; r.y += bk; r.z += bk; r.w += bk;
    ((float4*)(S + ((size_t)bz * ICn + o) * HWn + p0))[pq] = r;
  }
}

// ----------------------------------------------------------- softmax ------
// In-place softmax over the 4096 spatial elements of each (bz,o) row.
__global__ __launch_bounds__(256) void softmax_kernel(float* __restrict__ S) {
  __shared__ float row[HWn];
  __shared__ float red[4];
  const int t = threadIdx.x;
  float4* rowv = (float4*)row;
  float4* Sv = (float4*)(S + (size_t)blockIdx.x * HWn);
  float lmax = -1e30f;
#pragma unroll
  for (int i = 0; i < 4; ++i) {
    float4 v = Sv[t + 256 * i];
    rowv[t + 256 * i] = v;
    lmax = fmaxf(lmax, fmaxf(fmaxf(v.x, v.y), fmaxf(v.z, v.w)));
  }
#pragma unroll
  for (int off = 32; off; off >>= 1) lmax = fmaxf(lmax, __shfl_xor(lmax, off));
  if ((t & 63) == 0) red[t >> 6] = lmax;
  __syncthreads();
  lmax = fmaxf(fmaxf(red[0], red[1]), fmaxf(red[2], red[3]));
  float lsum = 0.f;
#pragma unroll
  for (int i = 0; i < 4; ++i) {
    float4 v = rowv[t + 256 * i];
    v.x = expf(v.x - lmax); v.y = expf(v.y - lmax);
    v.z = expf(v.z - lmax); v.w = expf(v.w - lmax);
    rowv[t + 256 * i] = v;
    lsum += v.x + v.y + v.z + v.w;
  }
#pragma unroll
  for (int off = 32; off; off >>= 1) lsum += __shfl_xor(lsum, off);
  __syncthreads();
  if ((t & 63) == 0) red[t >> 6] = lsum;
  __syncthreads();
  lsum = red[0] + red[1] + red[2] + red[3];
  float inv = 1.0f / lsum;
#pragma unroll
  for (int i = 0; i < 4; ++i) {
    float4 v = rowv[t + 256 * i];
    v.x *= inv; v.y *= inv; v.z *= inv; v.w *= inv;
    Sv[t + 256 * i] = v;
  }
}

// -------------------------------------------------------------- hsum ------
// hsum[bz,h,p] = sum_{i<32} S[bz, h*32+i, p]
__global__ __launch_bounds__(256) void hsum_kernel(const float* __restrict__ S,
                                                   float* __restrict__ hsum) {
  const int p4 = blockIdx.x * 256 + threadIdx.x;  // 0..1023
  const int hh = blockIdx.y, bz = blockIdx.z;
  const float* base = S + ((size_t)bz * ICn + hh * 32) * HWn;
  float4 a = make_float4(0.f, 0.f, 0.f, 0.f);
#pragma unroll
  for (int i = 0; i < 32; ++i) {
    float4 v = ((const float4*)(base + (size_t)i * HWn))[p4];
    a.x += v.x; a.y += v.y; a.z += v.z; a.w += v.w;
  }
  ((float4*)(hsum + ((size_t)bz * NHn + hh) * HWn))[p4] = a;
}

// ------------------------------------------------------------- gemm2 ------
// x2[bg,c,p] = x[bg,c,p] + sum_h (1/(hsum+1e-6)) * sum_{o in h} v[c,o]*S[bz,o,p]
// grid (32 ptiles, 2 ctiles, bc), block 256. C_TILE=64, P_TILE=128.
__global__ __launch_bounds__(256) void gemm2_kernel(
    const float* __restrict__ S, const float* __restrict__ vmat,
    const float* __restrict__ hsum, const float* __restrict__ x,
    float* __restrict__ x2, int b0) {
  const int pq = threadIdx.x & 31;
  const int cg = threadIdx.x >> 5;
  const int p0 = blockIdx.x * 128;
  const int c0 = blockIdx.y * 64;
  const int bz = blockIdx.z;
  const int bg = b0 + bz;
  __shared__ float sv[64][32];    // 8 KB
  __shared__ float ss[32][128];   // 16 KB
  float4 acc[8];
#pragma unroll
  for (int j = 0; j < 8; ++j) acc[j] = make_float4(0.f, 0.f, 0.f, 0.f);
  for (int hh = 0; hh < NHn; ++hh) {
    __syncthreads();
    for (int i = threadIdx.x; i < 64 * 8; i += 256) {
      int r = i >> 3, c4 = i & 7;
      ((float4*)sv[r])[c4] =
          ((const float4*)(vmat + (size_t)(c0 + r) * ICn + hh * 32))[c4];
    }
    for (int i = threadIdx.x; i < 32 * 32; i += 256) {
      int r = i >> 5, c4 = i & 31;
      ((float4*)ss[r])[c4] =
          ((const float4*)(S + ((size_t)bz * ICn + hh * 32 + r) * HWn + p0))[c4];
    }
    __syncthreads();
    float4 ph[8];
#pragma unroll
    for (int j = 0; j < 8; ++j) ph[j] = make_float4(0.f, 0.f, 0.f, 0.f);
    for (int o = 0; o < 32; ++o) {
      float4 s4 = ((float4*)ss[o])[pq];
#pragma unroll
      for (int j = 0; j < 8; ++j) {
        float vv = sv[cg * 8 + j][o];
        ph[j].x += vv * s4.x; ph[j].y += vv * s4.y;
        ph[j].z += vv * s4.z; ph[j].w += vv * s4.w;
      }
    }
    float4 hs = ((const float4*)(hsum + ((size_t)bz * NHn + hh) * HWn + p0))[pq];
    float4 r;
    r.x = 1.0f / (hs.x + 1e-6f); r.y = 1.0f / (hs.y + 1e-6f);
    r.z = 1.0f / (hs.z + 1e-6f); r.w = 1.0f / (hs.w + 1e-6f);
#pragma unroll
    for (int j = 0; j < 8; ++j) {
      acc[j].x += ph[j].x * r.x; acc[j].y += ph[j].y * r.y;
      acc[j].z += ph[j].z * r.z; acc[j].w += ph[j].w * r.w;
    }
  }
#pragma unroll
  for (int j = 0; j < 8; ++j) {
    int c = c0 + cg * 8 + j;
    float4 xv = ((const float4*)(x + ((size_t)bg * Cn + c) * HWn + p0))[pq];
    float4 o;
    o.x = xv.x + acc[j].x; o.y = xv.y + acc[j].y;
    o.z = xv.z + acc[j].z; o.w = xv.w + acc[j].w;
    ((float4*)(x2 + ((size_t)bg * Cn + c) * HWn + p0))[pq] = o;
  }
}

// ------------------------------------------------------------ conv3x3 -----
// Direct 3x3 SAME conv. Spatial tile 32(W) x 8(H), OC_TILE=64, per-thread:
// 1 position x 64 oc. Input tile staged in LDS (BN2 applied inline for conv1,
// zero padding exact). Weights read through wave-uniform addresses -> scalar
// loads (SMEM pipe), so the VALU only does FMAs.
// IN_GLOBAL / OUT_GLOBAL select absolute-batch (b0+bz) vs chunk-local (bz)
// indexing for the in / out (and resid, = out-side) tensors.
template <int IN_C, int OUT_C, bool DO_BN, bool DO_GELU, bool DO_RESID,
          bool IN_GLOBAL, bool OUT_GLOBAL>
__global__ __launch_bounds__(256) void conv3x3_kernel(
    const float* __restrict__ in, const float* __restrict__ wgt,
    const float* __restrict__ bias, const float* __restrict__ inv2,
    const float* __restrict__ beta2, const float* __restrict__ resid,
    float* __restrict__ out, int b0) {
  const int t = threadIdx.x;
  const int tx = t & 31, ty = t >> 5;
  const int x0 = (blockIdx.x & 1) * 32;
  const int y0 = (blockIdx.x >> 1) * 8;
  const int oc0 = blockIdx.y * 64;
  const int bz = blockIdx.z;
  const int bin = IN_GLOBAL ? (b0 + bz) : bz;
  const int bout = OUT_GLOBAL ? (b0 + bz) : bz;
  __shared__ float sin_t[4][10][36];  // 5.76 KB (34 cols used)
  float acc[64];
#pragma unroll
  for (int j = 0; j < 64; ++j) acc[j] = 0.f;
  const int xg = x0 + tx, yg = y0 + ty;

  for (int ic0 = 0; ic0 < IN_C; ic0 += 4) {
    __syncthreads();
    for (int i = t; i < 4 * 10 * 34; i += 256) {
      int icq = i / 340;
      int rem = i - icq * 340;
      int yy = rem / 34;
      int xx = rem - yy * 34;
      int gy = y0 - 1 + yy, gx = x0 - 1 + xx;
      float val = 0.f;
      if (gy >= 0 && gy < 64 && gx >= 0 && gx < 64) {
        val = in[(((size_t)bin * IN_C + ic0 + icq) * 64 + gy) * 64 + gx];
        if constexpr (DO_BN) val = val * inv2[ic0 + icq] + beta2[ic0 + icq];
      }
      sin_t[icq][yy][xx] = val;
    }
    __syncthreads();

    float iv[36];
#pragma unroll
    for (int icq = 0; icq < 4; ++icq)
#pragma unroll
      for (int kh = 0; kh < 3; ++kh)
#pragma unroll
        for (int kw = 0; kw < 3; ++kw)
          iv[icq * 9 + kh * 3 + kw] = sin_t[icq][ty + kh][tx + kw];

    const float* wbase = wgt + ((size_t)oc0 * IN_C + ic0) * 9;
#pragma unroll 16
    for (int j = 0; j < 64; ++j) {
      const float* wj = wbase + (size_t)j * IN_C * 9;  // wave-uniform -> s_load
      float a = acc[j];
#pragma unroll
      for (int q = 0; q < 36; ++q) a += wj[q] * iv[q];
      acc[j] = a;
    }
  }

#pragma unroll
  for (int j = 0; j < 64; ++j) {
    int oc = oc0 + j;
    float r = acc[j] + bias[oc];
    if constexpr (DO_GELU) r = 0.5f * r * (1.f + erff(r * 0.70710678118654752f));
    if constexpr (DO_RESID)
      r += resid[(((size_t)bout * OUT_C + oc) * 64 + yg) * 64 + xg];
    out[(((size_t)bout * OUT_C + oc) * 64 + yg) * 64 + xg] = r;
  }
}

// ----------------------------------------------------------------------- //
extern "C" void kernel_launch(void* const* d_in, const int* in_sizes, int n_in,
                              void* d_out, int out_size, void* d_ws,
                              size_t ws_size, hipStream_t stream) {
  const float* x = (const float*)d_in[0];
  const float* bn1_g = (const float*)d_in[1];
  const float* bn1_b = (const float*)d_in[2];
  const float* bn1_m = (const float*)d_in[3];
  const float* bn1_v = (const float*)d_in[4];
  const float* kmat = (const float*)d_in[5];
  const float* vmat = (const float*)d_in[6];
  const float* bn2_g = (const float*)d_in[7];
  const float* bn2_b = (const float*)d_in[8];
  const float* bn2_m = (const float*)d_in[9];
  const float* bn2_v = (const float*)d_in[10];
  const float* w1 = (const float*)d_in[11];
  const float* b1 = (const float*)d_in[12];
  const float* w2 = (const float*)d_in[13];
  const float* b2 = (const float*)d_in[14];
  float* out = (float*)d_out;

  // ---- chunk-size selection from the REAL ws_size (same every call) ----
  const size_t SM_PER = (size_t)HIDn * HWn;  // 2,097,152 fl (mid; covers S)
  const size_t HS_PER = (size_t)NHn * HWn;   //    32,768 fl
  const size_t CONSTF = 32768 + 256 + 128 + 128;  // 33,280 fl
  int bc = 32;
  while (bc > 1 &&
         (CONSTF + (size_t)bc * (SM_PER + HS_PER)) * sizeof(float) > ws_size)
    bc >>= 1;

  float* ws = (float*)d_ws;
  float* keff = ws;                 // 32,768
  float* biask = keff + 32768;      // 256
  float* inv2 = biask + 256;        // 128
  float* beta2 = inv2 + 128;        // 128
  float* SM = beta2 + 128;          // bc * SM_PER  (S then mid)
  float* hsum = SM + (size_t)bc * SM_PER;  // bc * HS_PER
  float* S = SM;
  float* mid = SM;
  float* x2 = out;  // x2 lives in d_out (conv2 finalizes in-place)

  prep_kernel<<<dim3(1), dim3(256), 0, stream>>>(
      bn1_g, bn1_b, bn1_m, bn1_v, kmat, bn2_g, bn2_b, bn2_m, bn2_v, keff,
      biask, inv2, beta2);

  for (int b0 = 0; b0 < Bn; b0 += bc) {
    gemm1_kernel<<<dim3(32, 4, bc), dim3(256), 0, stream>>>(x, keff, biask, S,
                                                            b0);
    softmax_kernel<<<dim3(bc * ICn), dim3(256), 0, stream>>>(S);
    hsum_kernel<<<dim3(4, NHn, bc), dim3(256), 0, stream>>>(S, hsum);
    gemm2_kernel<<<dim3(32, 2, bc), dim3(256), 0, stream>>>(S, vmat, hsum, x,
                                                            x2, b0);
    conv3x3_kernel<Cn, HIDn, true, true, false, true, false>
        <<<dim3(16, 8, bc), dim3(256), 0, stream>>>(x2, w1, b1, inv2, beta2,
                                                    nullptr, mid, b0);
    conv3x3_kernel<HIDn, Cn, false, false, true, false, true>
        <<<dim3(16, 2, bc), dim3(256), 0, stream>>>(mid, w2, b2, nullptr,
                                                    nullptr, x2, out, b0);
  }
}

// Round 4
// 1835.795 us; speedup vs baseline: 10.5210x; 10.5210x over previous
//
#include <hip/hip_runtime.h>
#include <hip/hip_bf16.h>
#include <math.h>

// EABlock, MFMA bf16-split implementation.
// Shapes: B=32, C=128, IC=256, NH=8, H=W=64 (HW=4096), HID=512.
//
// All GEMM-shaped work uses v_mfma_f32_16x16x32_bf16 with split-bf16
// operands (v = hi + lo, compute hi*hi + hi*lo + lo*hi -> ~fp32 accuracy).
// Block tile 128x128 (4 waves, 64x64 each, 4x4 fragments of 16x16).
// B staged in LDS k-innermost, k-dim padded 32->40 (80B col stride, uniform
// bank quads). A (weights) read from global (L2-resident), bypassing LDS.

#define Bn 32
#define Cn 128
#define ICn 256
#define NHn 8
#define HWn 4096
#define HIDn 512
#define GPAD 40

typedef __bf16 bf16x8 __attribute__((ext_vector_type(8)));
typedef float f32x4 __attribute__((ext_vector_type(4)));

__device__ __forceinline__ uint32_t bf16_hi_bits(float v) {
  uint32_t u = __float_as_uint(v);
  return (u + 0x7FFFu + ((u >> 16) & 1u)) >> 16;  // RNE to bf16
}
__device__ __forceinline__ float bf16_bits_f32(uint32_t b) {
  return __uint_as_float(b << 16);
}
__device__ __forceinline__ void split_bf16(float v, uint32_t& h, uint32_t& l) {
  h = bf16_hi_bits(v);
  float rem = v - bf16_bits_f32(h);
  l = bf16_hi_bits(rem);
}
// split 8 values and store 16B hi-plane + 16B lo-plane
__device__ __forceinline__ void split8_store(const float* v, ushort* dh,
                                             ushort* dl) {
  uint32_t hp[4], lp[4];
#pragma unroll
  for (int q = 0; q < 4; ++q) {
    uint32_t h0, l0, h1, l1;
    split_bf16(v[2 * q], h0, l0);
    split_bf16(v[2 * q + 1], h1, l1);
    hp[q] = h0 | (h1 << 16);
    lp[q] = l0 | (l1 << 16);
  }
  *(uint4*)dh = make_uint4(hp[0], hp[1], hp[2], hp[3]);
  *(uint4*)dl = make_uint4(lp[0], lp[1], lp[2], lp[3]);
}

#define MFMA(a, b, c) __builtin_amdgcn_mfma_f32_16x16x32_bf16((a), (b), (c), 0, 0, 0)

// ---------------------------------------------------------------- prep ----
__global__ __launch_bounds__(256) void prep_a_kernel(
    const float* __restrict__ bn1_g, const float* __restrict__ bn1_b,
    const float* __restrict__ bn1_m, const float* __restrict__ bn1_v,
    const float* __restrict__ kmat,
    const float* __restrict__ bn2_g, const float* __restrict__ bn2_b,
    const float* __restrict__ bn2_m, const float* __restrict__ bn2_v,
    float* __restrict__ keff, float* __restrict__ biask,
    float* __restrict__ inv2, float* __restrict__ beta2) {
  __shared__ float sinv1[Cn], sbeta1[Cn];
  const int t = threadIdx.x;  // 256
  if (t < Cn) {
    float i1 = bn1_g[t] / sqrtf(bn1_v[t] + 1e-5f);
    sinv1[t] = i1;
    sbeta1[t] = bn1_b[t] - bn1_m[t] * i1;
    float i2 = bn2_g[t] / sqrtf(bn2_v[t] + 1e-6f);
    inv2[t] = i2;
    beta2[t] = bn2_b[t] - bn2_m[t] * i2;
  }
  __syncthreads();
  float bk = 0.f;  // t = output channel o in [0,256)
  for (int c = 0; c < Cn; ++c) {
    float kv = kmat[t * Cn + c];
    keff[t * Cn + c] = kv * sinv1[c];
    bk += kv * sbeta1[c];
  }
  biask[t] = bk;
}

// split keff/vmat; transpose+split conv weights to [tap][oc][ic] planes.
__global__ __launch_bounds__(256) void prep_b_kernel(
    const float* __restrict__ keff, const float* __restrict__ vmat,
    const float* __restrict__ w1, const float* __restrict__ w2,
    ushort* __restrict__ k1h, ushort* __restrict__ k1l,
    ushort* __restrict__ vh, ushort* __restrict__ vl,
    ushort* __restrict__ wt1h, ushort* __restrict__ wt1l,
    ushort* __restrict__ wt2h, ushort* __restrict__ wt2l) {
  const int stride = gridDim.x * blockDim.x;
  const int tid0 = blockIdx.x * blockDim.x + threadIdx.x;
  uint32_t h, l;
  for (int i = tid0; i < ICn * Cn; i += stride) {
    split_bf16(keff[i], h, l); k1h[i] = (ushort)h; k1l[i] = (ushort)l;
  }
  for (int i = tid0; i < Cn * ICn; i += stride) {
    split_bf16(vmat[i], h, l); vh[i] = (ushort)h; vl[i] = (ushort)l;
  }
  for (int i = tid0; i < 9 * HIDn * Cn; i += stride) {
    int t = i / (HIDn * Cn);
    int rem = i - t * (HIDn * Cn);
    int oc = rem >> 7, ic = rem & 127;
    split_bf16(w1[(oc * Cn + ic) * 9 + t], h, l);
    wt1h[i] = (ushort)h; wt1l[i] = (ushort)l;
  }
  for (int i = tid0; i < 9 * Cn * HIDn; i += stride) {
    int t = i / (Cn * HIDn);
    int rem = i - t * (Cn * HIDn);
    int oc = rem >> 9, ic = rem & 511;
    split_bf16(w2[(oc * HIDn + ic) * 9 + t], h, l);
    wt2h[i] = (ushort)h; wt2l[i] = (ushort)l;
  }
}

// ------------------------------------------------------------- gemm1 ------
// S[bz,o,p] = biask[o] + sum_c keff[o,c]*x[b0+bz,c,p].  M=256,N=4096,K=128.
// grid (32 ptiles, 2 octiles, bc), block 256 (4 waves 2x2).
__global__ __launch_bounds__(256) void gemm1_mfma(
    const float* __restrict__ x, const ushort* __restrict__ k1h,
    const ushort* __restrict__ k1l, const float* __restrict__ biask,
    float* __restrict__ S, int b0) {
  const int tid = threadIdx.x, lane = tid & 63, wave = tid >> 6;
  const int wm = wave >> 1, wn = wave & 1;
  const int l15 = lane & 15, lg = lane >> 4;
  const int p0 = blockIdx.x * 128;
  const int oc0 = blockIdx.y * 128;
  const int bg = b0 + blockIdx.z;
  __shared__ __align__(16) ushort Xh[128 * GPAD];
  __shared__ __align__(16) ushort Xl[128 * GPAD];
  f32x4 acc[4][4] = {};
  for (int c0 = 0; c0 < Cn; c0 += 32) {
    __syncthreads();
    for (int i = tid; i < 512; i += 256) {
      int p = i & 127, g = i >> 7;
      const float* src = x + ((size_t)bg * Cn + c0 + g * 8) * HWn + p0 + p;
      float v[8];
#pragma unroll
      for (int j = 0; j < 8; ++j) v[j] = src[(size_t)j * HWn];
      split8_store(v, &Xh[p * GPAD + g * 8], &Xl[p * GPAD + g * 8]);
    }
    __syncthreads();
    bf16x8 Bh[4], Bl[4];
#pragma unroll
    for (int nf = 0; nf < 4; ++nf) {
      int n = wn * 64 + nf * 16 + l15;
      Bh[nf] = *(const bf16x8*)&Xh[n * GPAD + lg * 8];
      Bl[nf] = *(const bf16x8*)&Xl[n * GPAD + lg * 8];
    }
#pragma unroll
    for (int mf = 0; mf < 4; ++mf) {
      int oc = oc0 + wm * 64 + mf * 16 + l15;
      bf16x8 Ah = *(const bf16x8*)(k1h + (size_t)oc * Cn + c0 + lg * 8);
      bf16x8 Al = *(const bf16x8*)(k1l + (size_t)oc * Cn + c0 + lg * 8);
#pragma unroll
      for (int nf = 0; nf < 4; ++nf) {
        acc[mf][nf] = MFMA(Ah, Bh[nf], acc[mf][nf]);
        acc[mf][nf] = MFMA(Ah, Bl[nf], acc[mf][nf]);
        acc[mf][nf] = MFMA(Al, Bh[nf], acc[mf][nf]);
      }
    }
  }
#pragma unroll
  for (int mf = 0; mf < 4; ++mf)
#pragma unroll
    for (int r = 0; r < 4; ++r) {
      int oc = oc0 + wm * 64 + mf * 16 + lg * 4 + r;
      float bk = biask[oc];
#pragma unroll
      for (int nf = 0; nf < 4; ++nf) {
        int p = p0 + wn * 64 + nf * 16 + l15;
        S[((size_t)blockIdx.z * ICn + oc) * HWn + p] = acc[mf][nf][r] + bk;
      }
    }
}

// ----------------------------------------------------------- softmax ------
__global__ __launch_bounds__(256) void softmax_kernel(float* __restrict__ S) {
  __shared__ float row[HWn];
  __shared__ float red[4];
  const int t = threadIdx.x;
  float4* rowv = (float4*)row;
  float4* Sv = (float4*)(S + (size_t)blockIdx.x * HWn);
  float lmax = -1e30f;
#pragma unroll
  for (int i = 0; i < 4; ++i) {
    float4 v = Sv[t + 256 * i];
    rowv[t + 256 * i] = v;
    lmax = fmaxf(lmax, fmaxf(fmaxf(v.x, v.y), fmaxf(v.z, v.w)));
  }
#pragma unroll
  for (int off = 32; off; off >>= 1) lmax = fmaxf(lmax, __shfl_xor(lmax, off));
  if ((t & 63) == 0) red[t >> 6] = lmax;
  __syncthreads();
  lmax = fmaxf(fmaxf(red[0], red[1]), fmaxf(red[2], red[3]));
  float lsum = 0.f;
#pragma unroll
  for (int i = 0; i < 4; ++i) {
    float4 v = rowv[t + 256 * i];
    v.x = expf(v.x - lmax); v.y = expf(v.y - lmax);
    v.z = expf(v.z - lmax); v.w = expf(v.w - lmax);
    rowv[t + 256 * i] = v;
    lsum += v.x + v.y + v.z + v.w;
  }
#pragma unroll
  for (int off = 32; off; off >>= 1) lsum += __shfl_xor(lsum, off);
  __syncthreads();
  if ((t & 63) == 0) red[t >> 6] = lsum;
  __syncthreads();
  lsum = red[0] + red[1] + red[2] + red[3];
  float inv = 1.0f / lsum;
#pragma unroll
  for (int i = 0; i < 4; ++i) {
    float4 v = rowv[t + 256 * i];
    v.x *= inv; v.y *= inv; v.z *= inv; v.w *= inv;
    Sv[t + 256 * i] = v;
  }
}

// -------------------------------------------------------------- hsum ------
__global__ __launch_bounds__(256) void hsum_kernel(const float* __restrict__ S,
                                                   float* __restrict__ hsum) {
  const int p4 = blockIdx.x * 256 + threadIdx.x;
  const int hh = blockIdx.y, bz = blockIdx.z;
  const float* base = S + ((size_t)bz * ICn + hh * 32) * HWn;
  float4 a = make_float4(0.f, 0.f, 0.f, 0.f);
#pragma unroll
  for (int i = 0; i < 32; ++i) {
    float4 v = ((const float4*)(base + (size_t)i * HWn))[p4];
    a.x += v.x; a.y += v.y; a.z += v.z; a.w += v.w;
  }
  ((float4*)(hsum + ((size_t)bz * NHn + hh) * HWn))[p4] = a;
}

// ------------------------------------------------------------- gemm2 ------
// x2[bg,c,p] = x[bg,c,p] + sum_o vmat[c,o] * (S[bz,o,p]*r[bz,head(o),p]).
// M=128,N=4096,K=256 (8 chunks of 32 = heads; r folded at staging).
// grid (32 ptiles, 1, bc).
__global__ __launch_bounds__(256) void gemm2_mfma(
    const float* __restrict__ S, const ushort* __restrict__ vh,
    const ushort* __restrict__ vl, const float* __restrict__ hsum,
    const float* __restrict__ x, float* __restrict__ x2, int b0) {
  const int tid = threadIdx.x, lane = tid & 63, wave = tid >> 6;
  const int wm = wave >> 1, wn = wave & 1;
  const int l15 = lane & 15, lg = lane >> 4;
  const int p0 = blockIdx.x * 128;
  const int bz = blockIdx.z, bg = b0 + bz;
  __shared__ __align__(16) ushort Xh[128 * GPAD];
  __shared__ __align__(16) ushort Xl[128 * GPAD];
  f32x4 acc[4][4] = {};
  for (int hh = 0; hh < NHn; ++hh) {  // chunk == head (32 o-rows)
    __syncthreads();
    for (int i = tid; i < 512; i += 256) {
      int p = i & 127, g = i >> 7;
      const float* src = S + ((size_t)bz * ICn + hh * 32 + g * 8) * HWn + p0 + p;
      float rr = 1.0f / (hsum[((size_t)bz * NHn + hh) * HWn + p0 + p] + 1e-6f);
      float v[8];
#pragma unroll
      for (int j = 0; j < 8; ++j) v[j] = src[(size_t)j * HWn] * rr;
      split8_store(v, &Xh[p * GPAD + g * 8], &Xl[p * GPAD + g * 8]);
    }
    __syncthreads();
    bf16x8 Bh[4], Bl[4];
#pragma unroll
    for (int nf = 0; nf < 4; ++nf) {
      int n = wn * 64 + nf * 16 + l15;
      Bh[nf] = *(const bf16x8*)&Xh[n * GPAD + lg * 8];
      Bl[nf] = *(const bf16x8*)&Xl[n * GPAD + lg * 8];
    }
#pragma unroll
    for (int mf = 0; mf < 4; ++mf) {
      int c = wm * 64 + mf * 16 + l15;
      bf16x8 Ah = *(const bf16x8*)(vh + (size_t)c * ICn + hh * 32 + lg * 8);
      bf16x8 Al = *(const bf16x8*)(vl + (size_t)c * ICn + hh * 32 + lg * 8);
#pragma unroll
      for (int nf = 0; nf < 4; ++nf) {
        acc[mf][nf] = MFMA(Ah, Bh[nf], acc[mf][nf]);
        acc[mf][nf] = MFMA(Ah, Bl[nf], acc[mf][nf]);
        acc[mf][nf] = MFMA(Al, Bh[nf], acc[mf][nf]);
      }
    }
  }
#pragma unroll
  for (int mf = 0; mf < 4; ++mf)
#pragma unroll
    for (int r = 0; r < 4; ++r) {
      int c = wm * 64 + mf * 16 + lg * 4 + r;
#pragma unroll
      for (int nf = 0; nf < 4; ++nf) {
        int p = p0 + wn * 64 + nf * 16 + l15;
        size_t off = ((size_t)bg * Cn + c) * HWn + p;
        x2[off] = x[off] + acc[mf][nf][r];
      }
    }
}

// ------------------------------------------------------------ conv3x3 -----
// Implicit-GEMM 3x3 SAME conv. Block tile 128oc x 128p (2 rows x 64 cols).
// Input staged per 32-ic chunk into haloed LDS [4 rows][66 cols][40 ic-pad]
// (h/l planes); 9 taps = 9 shifted B-reads. Weights Wt[tap][oc][ic] from
// global (L2). conv1: BN at staging (IN-BOUNDS ONLY -- reference zero-pads
// the BN output), GELU+pack-u32 epilogue. conv2: packed input, residual f32
// epilogue.
template <int IN_C, int OUT_C, bool IN_PACKED, bool DO_BN, bool GELU_PACK,
          bool DO_RESID, bool IN_ABS, bool OUT_ABS>
__global__ __launch_bounds__(256) void conv_mfma(
    const void* __restrict__ in_v, const ushort* __restrict__ wth,
    const ushort* __restrict__ wtl, const float* __restrict__ bias,
    const float* __restrict__ inv2, const float* __restrict__ beta2,
    const float* __restrict__ resid, void* __restrict__ out_v, int b0) {
  const int tid = threadIdx.x, lane = tid & 63, wave = tid >> 6;
  const int wm = wave >> 1, wn = wave & 1;
  const int l15 = lane & 15, lg = lane >> 4;
  const int p0 = blockIdx.x * 128;
  const int y0 = p0 >> 6;  // two output rows y0, y0+1
  const int oc0 = blockIdx.y * 128;
  const int bz = blockIdx.z;
  const int bin = IN_ABS ? (b0 + bz) : bz;
  const int bout = OUT_ABS ? (b0 + bz) : bz;
  __shared__ __align__(16) ushort Xh[4 * 66 * GPAD];
  __shared__ __align__(16) ushort Xl[4 * 66 * GPAD];
  f32x4 acc[4][4] = {};

  for (int ic0 = 0; ic0 < IN_C; ic0 += 32) {
    __syncthreads();
    for (int i = tid; i < 4 * 66 * 4; i += 256) {
      int c = i % 66;
      int rg = i / 66;
      int r = rg & 3, g = rg >> 2;
      int gy = y0 - 1 + r, gx = c - 1;
      bool inb = (gy >= 0 && gy < 64 && gx >= 0 && gx < 64);
      ushort* dh = &Xh[(r * 66 + c) * GPAD + g * 8];
      ushort* dl = &Xl[(r * 66 + c) * GPAD + g * 8];
      if constexpr (IN_PACKED) {
        const uint32_t* src = (const uint32_t*)in_v +
                              ((size_t)bin * IN_C + ic0 + g * 8) * HWn +
                              gy * 64 + gx;
        uint32_t hp[4], lp[4];
#pragma unroll
        for (int q = 0; q < 4; ++q) {
          uint32_t u0 = inb ? src[(size_t)(2 * q) * HWn] : 0u;
          uint32_t u1 = inb ? src[(size_t)(2 * q + 1) * HWn] : 0u;
          hp[q] = (u0 >> 16) | (u1 & 0xFFFF0000u);
          lp[q] = (u0 & 0xFFFFu) | (u1 << 16);
        }
        *(uint4*)dh = make_uint4(hp[0], hp[1], hp[2], hp[3]);
        *(uint4*)dl = make_uint4(lp[0], lp[1], lp[2], lp[3]);
      } else {
        const float* src = (const float*)in_v +
                           ((size_t)bin * IN_C + ic0 + g * 8) * HWn + gy * 64 +
                           gx;
        float v[8];
#pragma unroll
        for (int j = 0; j < 8; ++j) {
          float val = 0.f;
          if (inb) {  // BN only in-bounds: reference zero-pads the BN OUTPUT
            val = src[(size_t)j * HWn];
            if constexpr (DO_BN)
              val = val * inv2[ic0 + g * 8 + j] + beta2[ic0 + g * 8 + j];
          }
          v[j] = val;
        }
        split8_store(v, dh, dl);
      }
    }
    __syncthreads();

    for (int kh = 0; kh < 3; ++kh)
      for (int kw = 0; kw < 3; ++kw) {
        const int tap = kh * 3 + kw;
        bf16x8 Bh[4], Bl[4];
#pragma unroll
        for (int nf = 0; nf < 4; ++nf) {
          int n = wn * 64 + nf * 16 + l15;
          int addr = (((n >> 6) + kh) * 66 + (n & 63) + kw) * GPAD + lg * 8;
          Bh[nf] = *(const bf16x8*)&Xh[addr];
          Bl[nf] = *(const bf16x8*)&Xl[addr];
        }
#pragma unroll
        for (int mf = 0; mf < 4; ++mf) {
          int oc = oc0 + wm * 64 + mf * 16 + l15;
          size_t woff = ((size_t)tap * OUT_C + oc) * IN_C + ic0 + lg * 8;
          bf16x8 Ah = *(const bf16x8*)(wth + woff);
          bf16x8 Al = *(const bf16x8*)(wtl + woff);
#pragma unroll
          for (int nf = 0; nf < 4; ++nf) {
            acc[mf][nf] = MFMA(Ah, Bh[nf], acc[mf][nf]);
            acc[mf][nf] = MFMA(Ah, Bl[nf], acc[mf][nf]);
            acc[mf][nf] = MFMA(Al, Bh[nf], acc[mf][nf]);
          }
        }
      }
  }

#pragma unroll
  for (int mf = 0; mf < 4; ++mf)
#pragma unroll
    for (int r = 0; r < 4; ++r) {
      int oc = oc0 + wm * 64 + mf * 16 + lg * 4 + r;
      float bv = bias[oc];
#pragma unroll
      for (int nf = 0; nf < 4; ++nf) {
        int n = wn * 64 + nf * 16 + l15;
        size_t off = ((size_t)bout * OUT_C + oc) * HWn + p0 + n;
        float vv = acc[mf][nf][r] + bv;
        if constexpr (GELU_PACK) {
          vv = 0.5f * vv * (1.f + erff(vv * 0.70710678118654752f));
          uint32_t h, l;
          split_bf16(vv, h, l);
          ((uint32_t*)out_v)[off] = (h << 16) | l;
        } else {
          if constexpr (DO_RESID) vv += resid[off];
          ((float*)out_v)[off] = vv;
        }
      }
    }
}

// ----------------------------------------------------------------------- //
extern "C" void kernel_launch(void* const* d_in, const int* in_sizes, int n_in,
                              void* d_out, int out_size, void* d_ws,
                              size_t ws_size, hipStream_t stream) {
  const float* x = (const float*)d_in[0];
  const float* bn1_g = (const float*)d_in[1];
  const float* bn1_b = (const float*)d_in[2];
  const float* bn1_m = (const float*)d_in[3];
  const float* bn1_v = (const float*)d_in[4];
  const float* kmat = (const float*)d_in[5];
  const float* vmat = (const float*)d_in[6];
  const float* bn2_g = (const float*)d_in[7];
  const float* bn2_b = (const float*)d_in[8];
  const float* bn2_m = (const float*)d_in[9];
  const float* bn2_v = (const float*)d_in[10];
  const float* w1 = (const float*)d_in[11];
  const float* b1 = (const float*)d_in[12];
  const float* w2 = (const float*)d_in[13];
  const float* b2 = (const float*)d_in[14];
  float* out = (float*)d_out;

  // ---- workspace carve (bytes) ----
  char* p = (char*)d_ws;
  float* keff = (float*)p;        p += (size_t)ICn * Cn * 4;      // 131072
  float* biask = (float*)p;       p += 1024;
  float* inv2 = (float*)p;        p += 512;
  float* beta2 = (float*)p;       p += 512;
  ushort* k1h = (ushort*)p;       p += (size_t)ICn * Cn * 2;
  ushort* k1l = (ushort*)p;       p += (size_t)ICn * Cn * 2;
  ushort* vh = (ushort*)p;        p += (size_t)Cn * ICn * 2;
  ushort* vl = (ushort*)p;        p += (size_t)Cn * ICn * 2;
  ushort* wt1h = (ushort*)p;      p += (size_t)9 * HIDn * Cn * 2;
  ushort* wt1l = (ushort*)p;      p += (size_t)9 * HIDn * Cn * 2;
  ushort* wt2h = (ushort*)p;      p += (size_t)9 * Cn * HIDn * 2;
  ushort* wt2l = (ushort*)p;      p += (size_t)9 * Cn * HIDn * 2;
  size_t const_bytes = (size_t)(p - (char*)d_ws);

  const size_t SM_BYTES = (size_t)HIDn * HWn * 4;  // per sample (mid; covers S)
  const size_t HS_BYTES = (size_t)NHn * HWn * 4;
  int bc = 32;
  while (bc > 1 && const_bytes + (size_t)bc * (SM_BYTES + HS_BYTES) > ws_size)
    bc >>= 1;
  float* S = (float*)p;            // also mid region (u32), S dead by conv1
  uint32_t* mid = (uint32_t*)p;
  float* hsum = (float*)(p + (size_t)bc * SM_BYTES);
  float* x2 = out;  // x2 lives in d_out; conv2 finalizes in-place

  prep_a_kernel<<<dim3(1), dim3(256), 0, stream>>>(
      bn1_g, bn1_b, bn1_m, bn1_v, kmat, bn2_g, bn2_b, bn2_m, bn2_v, keff,
      biask, inv2, beta2);
  prep_b_kernel<<<dim3(1024), dim3(256), 0, stream>>>(
      keff, vmat, w1, w2, k1h, k1l, vh, vl, wt1h, wt1l, wt2h, wt2l);

  for (int b0 = 0; b0 < Bn; b0 += bc) {
    gemm1_mfma<<<dim3(32, 2, bc), dim3(256), 0, stream>>>(x, k1h, k1l, biask,
                                                          S, b0);
    softmax_kernel<<<dim3(bc * ICn), dim3(256), 0, stream>>>(S);
    hsum_kernel<<<dim3(4, NHn, bc), dim3(256), 0, stream>>>(S, hsum);
    gemm2_mfma<<<dim3(32, 1, bc), dim3(256), 0, stream>>>(S, vh, vl, hsum, x,
                                                          x2, b0);
    conv_mfma<Cn, HIDn, false, true, true, false, true, false>
        <<<dim3(32, 4, bc), dim3(256), 0, stream>>>(x2, wt1h, wt1l, b1, inv2,
                                                    beta2, nullptr, mid, b0);
    conv_mfma<HIDn, Cn, true, false, false, true, false, true>
        <<<dim3(32, 1, bc), dim3(256), 0, stream>>>(mid, wt2h, wt2l, b2,
                                                    nullptr, nullptr, x2, out,
                                                    b0);
  }
}

// Round 5
// 1443.498 us; speedup vs baseline: 13.3802x; 1.2718x over previous
//
#include <hip/hip_runtime.h>
#include <hip/hip_bf16.h>
#include <math.h>

// EABlock, MFMA bf16 2-term-split implementation.
// Shapes: B=32, C=128, IC=256, NH=8, H=W=64 (HW=4096), HID=512.
//
// GEMM work uses v_mfma_f32_16x16x32_bf16. Weights are split hi+lo bf16
// (A operand, 2 MFMA per pair -> fp32-grade weight precision); activations
// are plain bf16 (B operand, single LDS plane). Weights are pre-swizzled by
// prep_b into per-wave fragment blocks: frag f=(tap*NOB+ob)*NIB+ib holds
// 64 lanes x 8 bf16 = 1KB contiguous; lane loads base+lane*16 (coalesced).
// mid (conv1->conv2) is NHWC bf16.

#define Bn 32
#define Cn 128
#define ICn 256
#define NHn 8
#define HWn 4096
#define HIDn 512
#define GPAD 40

typedef __bf16 bf16x8 __attribute__((ext_vector_type(8)));
typedef float f32x4 __attribute__((ext_vector_type(4)));

__device__ __forceinline__ uint32_t bf16r(float v) {
  uint32_t u = __float_as_uint(v);
  return (u + 0x7FFFu + ((u >> 16) & 1u)) >> 16;  // RNE to bf16 bits
}
__device__ __forceinline__ void split_bf16(float v, uint32_t& h, uint32_t& l) {
  h = bf16r(v);
  float rem = v - __uint_as_float(h << 16);
  l = bf16r(rem);
}
__device__ __forceinline__ uint4 pack8(const float* v) {
  uint32_t w[4];
#pragma unroll
  for (int q = 0; q < 4; ++q)
    w[q] = bf16r(v[2 * q]) | (bf16r(v[2 * q + 1]) << 16);
  return make_uint4(w[0], w[1], w[2], w[3]);
}
#define MFMA(a, b, c) __builtin_amdgcn_mfma_f32_16x16x32_bf16((a), (b), (c), 0, 0, 0)

// ---------------------------------------------------------------- prep ----
__global__ __launch_bounds__(256) void prep_a_kernel(
    const float* __restrict__ bn1_g, const float* __restrict__ bn1_b,
    const float* __restrict__ bn1_m, const float* __restrict__ bn1_v,
    const float* __restrict__ kmat,
    const float* __restrict__ bn2_g, const float* __restrict__ bn2_b,
    const float* __restrict__ bn2_m, const float* __restrict__ bn2_v,
    float* __restrict__ keff, float* __restrict__ biask,
    float* __restrict__ inv2, float* __restrict__ beta2) {
  __shared__ float sinv1[Cn], sbeta1[Cn];
  const int t = threadIdx.x;  // 256
  if (t < Cn) {
    float i1 = bn1_g[t] / sqrtf(bn1_v[t] + 1e-5f);
    sinv1[t] = i1;
    sbeta1[t] = bn1_b[t] - bn1_m[t] * i1;
    float i2 = bn2_g[t] / sqrtf(bn2_v[t] + 1e-6f);
    inv2[t] = i2;
    beta2[t] = bn2_b[t] - bn2_m[t] * i2;
  }
  __syncthreads();
  float bk = 0.f;  // t = output channel o in [0,256)
  for (int c = 0; c < Cn; ++c) {
    float kv = kmat[t * Cn + c];
    keff[t * Cn + c] = kv * sinv1[c];
    bk += kv * sbeta1[c];
  }
  biask[t] = bk;
}

// Re-lay weights into per-wave fragment blocks (split hi/lo planes).
// dest d: e=d&7, lane=(d>>3)&63, f=d>>9; f=(tap*NOB+ob)*NIB+ib;
// oc=ob*16+(lane&15), k=ib*32+(lane>>4)*8+e.
__global__ __launch_bounds__(256) void prep_b_kernel(
    const float* __restrict__ keff, const float* __restrict__ vmat,
    const float* __restrict__ w1, const float* __restrict__ w2,
    ushort* __restrict__ k1h, ushort* __restrict__ k1l,
    ushort* __restrict__ vh, ushort* __restrict__ vl,
    ushort* __restrict__ wt1h, ushort* __restrict__ wt1l,
    ushort* __restrict__ wt2h, ushort* __restrict__ wt2l) {
  const int stride = gridDim.x * blockDim.x;
  const int tid0 = blockIdx.x * blockDim.x + threadIdx.x;
  uint32_t h, l;
  // k1: M=256 (NOB=16), K=128 (NIB=4), 1 tap
  for (int d = tid0; d < ICn * Cn; d += stride) {
    int e = d & 7, lane = (d >> 3) & 63, f = d >> 9;
    int ib = f & 3, ob = f >> 2;
    int oc = ob * 16 + (lane & 15), k = ib * 32 + (lane >> 4) * 8 + e;
    split_bf16(keff[oc * Cn + k], h, l);
    k1h[d] = (ushort)h; k1l[d] = (ushort)l;
  }
  // v: M=128 (NOB=8), K=256 (NIB=8), 1 tap
  for (int d = tid0; d < Cn * ICn; d += stride) {
    int e = d & 7, lane = (d >> 3) & 63, f = d >> 9;
    int ib = f & 7, ob = f >> 3;
    int oc = ob * 16 + (lane & 15), k = ib * 32 + (lane >> 4) * 8 + e;
    split_bf16(vmat[oc * ICn + k], h, l);
    vh[d] = (ushort)h; vl[d] = (ushort)l;
  }
  // wt1: 9 taps, M=512 (NOB=32), K=128 (NIB=4)
  for (int d = tid0; d < 9 * HIDn * Cn; d += stride) {
    int e = d & 7, lane = (d >> 3) & 63, f = d >> 9;
    int ib = f & 3, obt = f >> 2;
    int ob = obt & 31, tap = obt >> 5;
    int oc = ob * 16 + (lane & 15), k = ib * 32 + (lane >> 4) * 8 + e;
    split_bf16(w1[(oc * Cn + k) * 9 + tap], h, l);
    wt1h[d] = (ushort)h; wt1l[d] = (ushort)l;
  }
  // wt2: 9 taps, M=128 (NOB=8), K=512 (NIB=16)
  for (int d = tid0; d < 9 * Cn * HIDn; d += stride) {
    int e = d & 7, lane = (d >> 3) & 63, f = d >> 9;
    int ib = f & 15, obt = f >> 4;
    int ob = obt & 7, tap = obt >> 3;
    int oc = ob * 16 + (lane & 15), k = ib * 32 + (lane >> 4) * 8 + e;
    split_bf16(w2[(oc * HIDn + k) * 9 + tap], h, l);
    wt2h[d] = (ushort)h; wt2l[d] = (ushort)l;
  }
}

// ------------------------------------------------------------- gemm1 ------
// S[bz,o,p] = biask[o] + sum_c keff[o,c]*x[b0+bz,c,p].  M=256,N=4096,K=128.
__global__ __launch_bounds__(256, 4) void gemm1_mfma(
    const float* __restrict__ x, const ushort* __restrict__ k1h,
    const ushort* __restrict__ k1l, const float* __restrict__ biask,
    float* __restrict__ S, int b0) {
  const int tid = threadIdx.x, lane = tid & 63, wave = tid >> 6;
  const int wm = wave >> 1, wn = wave & 1;
  const int l15 = lane & 15, lg = lane >> 4;
  const int p0 = blockIdx.x * 128;
  const int oc0 = blockIdx.y * 128;
  const int bg = b0 + blockIdx.z;
  __shared__ __align__(16) ushort Xb[128 * GPAD];  // 10 KB
  f32x4 acc[4][4] = {};
  for (int c0 = 0; c0 < Cn; c0 += 32) {
    __syncthreads();
    for (int i = tid; i < 512; i += 256) {
      int p = i & 127, g = i >> 7;
      const float* src = x + ((size_t)bg * Cn + c0 + g * 8) * HWn + p0 + p;
      float v[8];
#pragma unroll
      for (int j = 0; j < 8; ++j) v[j] = src[(size_t)j * HWn];
      *(uint4*)&Xb[p * GPAD + g * 8] = pack8(v);
    }
    __syncthreads();
    bf16x8 Bf[4];
#pragma unroll
    for (int nf = 0; nf < 4; ++nf)
      Bf[nf] = *(const bf16x8*)&Xb[(wn * 64 + nf * 16 + l15) * GPAD + lg * 8];
#pragma unroll
    for (int mf = 0; mf < 4; ++mf) {
      int fidx = ((oc0 >> 4) + wm * 4 + mf) * 4 + (c0 >> 5);
      bf16x8 Ah = *(const bf16x8*)(k1h + (size_t)fidx * 512 + lane * 8);
      bf16x8 Al = *(const bf16x8*)(k1l + (size_t)fidx * 512 + lane * 8);
#pragma unroll
      for (int nf = 0; nf < 4; ++nf)
        acc[mf][nf] = MFMA(Al, Bf[nf], MFMA(Ah, Bf[nf], acc[mf][nf]));
    }
  }
#pragma unroll
  for (int mf = 0; mf < 4; ++mf)
#pragma unroll
    for (int r = 0; r < 4; ++r) {
      int oc = oc0 + wm * 64 + mf * 16 + lg * 4 + r;
      float bk = biask[oc];
#pragma unroll
      for (int nf = 0; nf < 4; ++nf) {
        int p = p0 + wn * 64 + nf * 16 + l15;
        S[((size_t)blockIdx.z * ICn + oc) * HWn + p] = acc[mf][nf][r] + bk;
      }
    }
}

// ----------------------------------------------------------- softmax ------
__global__ __launch_bounds__(256) void softmax_kernel(float* __restrict__ S) {
  __shared__ float row[HWn];
  __shared__ float red[4];
  const int t = threadIdx.x;
  float4* rowv = (float4*)row;
  float4* Sv = (float4*)(S + (size_t)blockIdx.x * HWn);
  float lmax = -1e30f;
#pragma unroll
  for (int i = 0; i < 4; ++i) {
    float4 v = Sv[t + 256 * i];
    rowv[t + 256 * i] = v;
    lmax = fmaxf(lmax, fmaxf(fmaxf(v.x, v.y), fmaxf(v.z, v.w)));
  }
#pragma unroll
  for (int off = 32; off; off >>= 1) lmax = fmaxf(lmax, __shfl_xor(lmax, off));
  if ((t & 63) == 0) red[t >> 6] = lmax;
  __syncthreads();
  lmax = fmaxf(fmaxf(red[0], red[1]), fmaxf(red[2], red[3]));
  float lsum = 0.f;
#pragma unroll
  for (int i = 0; i < 4; ++i) {
    float4 v = rowv[t + 256 * i];
    v.x = expf(v.x - lmax); v.y = expf(v.y - lmax);
    v.z = expf(v.z - lmax); v.w = expf(v.w - lmax);
    rowv[t + 256 * i] = v;
    lsum += v.x + v.y + v.z + v.w;
  }
#pragma unroll
  for (int off = 32; off; off >>= 1) lsum += __shfl_xor(lsum, off);
  __syncthreads();
  if ((t & 63) == 0) red[t >> 6] = lsum;
  __syncthreads();
  lsum = red[0] + red[1] + red[2] + red[3];
  float inv = 1.0f / lsum;
#pragma unroll
  for (int i = 0; i < 4; ++i) {
    float4 v = rowv[t + 256 * i];
    v.x *= inv; v.y *= inv; v.z *= inv; v.w *= inv;
    Sv[t + 256 * i] = v;
  }
}

// -------------------------------------------------------------- hsum ------
__global__ __launch_bounds__(256) void hsum_kernel(const float* __restrict__ S,
                                                   float* __restrict__ hsum) {
  const int p4 = blockIdx.x * 256 + threadIdx.x;
  const int hh = blockIdx.y, bz = blockIdx.z;
  const float* base = S + ((size_t)bz * ICn + hh * 32) * HWn;
  float4 a = make_float4(0.f, 0.f, 0.f, 0.f);
#pragma unroll
  for (int i = 0; i < 32; ++i) {
    float4 v = ((const float4*)(base + (size_t)i * HWn))[p4];
    a.x += v.x; a.y += v.y; a.z += v.z; a.w += v.w;
  }
  ((float4*)(hsum + ((size_t)bz * NHn + hh) * HWn))[p4] = a;
}

// ------------------------------------------------------------- gemm2 ------
// x2[bg,c,p] = x[bg,c,p] + sum_o vmat[c,o]*(S[bz,o,p]*rr[bz,head,p]).
__global__ __launch_bounds__(256, 4) void gemm2_mfma(
    const float* __restrict__ S, const ushort* __restrict__ vh,
    const ushort* __restrict__ vl, const float* __restrict__ hsum,
    const float* __restrict__ x, float* __restrict__ x2, int b0) {
  const int tid = threadIdx.x, lane = tid & 63, wave = tid >> 6;
  const int wm = wave >> 1, wn = wave & 1;
  const int l15 = lane & 15, lg = lane >> 4;
  const int p0 = blockIdx.x * 128;
  const int bz = blockIdx.z, bg = b0 + bz;
  __shared__ __align__(16) ushort Xb[128 * GPAD];
  f32x4 acc[4][4] = {};
  for (int hh = 0; hh < NHn; ++hh) {  // K chunk == head (32 o-rows)
    __syncthreads();
    for (int i = tid; i < 512; i += 256) {
      int p = i & 127, g = i >> 7;
      const float* src = S + ((size_t)bz * ICn + hh * 32 + g * 8) * HWn + p0 + p;
      float rr = 1.0f / (hsum[((size_t)bz * NHn + hh) * HWn + p0 + p] + 1e-6f);
      float v[8];
#pragma unroll
      for (int j = 0; j < 8; ++j) v[j] = src[(size_t)j * HWn] * rr;
      *(uint4*)&Xb[p * GPAD + g * 8] = pack8(v);
    }
    __syncthreads();
    bf16x8 Bf[4];
#pragma unroll
    for (int nf = 0; nf < 4; ++nf)
      Bf[nf] = *(const bf16x8*)&Xb[(wn * 64 + nf * 16 + l15) * GPAD + lg * 8];
#pragma unroll
    for (int mf = 0; mf < 4; ++mf) {
      int fidx = (wm * 4 + mf) * 8 + hh;
      bf16x8 Ah = *(const bf16x8*)(vh + (size_t)fidx * 512 + lane * 8);
      bf16x8 Al = *(const bf16x8*)(vl + (size_t)fidx * 512 + lane * 8);
#pragma unroll
      for (int nf = 0; nf < 4; ++nf)
        acc[mf][nf] = MFMA(Al, Bf[nf], MFMA(Ah, Bf[nf], acc[mf][nf]));
    }
  }
#pragma unroll
  for (int mf = 0; mf < 4; ++mf)
#pragma unroll
    for (int r = 0; r < 4; ++r) {
      int c = wm * 64 + mf * 16 + lg * 4 + r;
#pragma unroll
      for (int nf = 0; nf < 4; ++nf) {
        int p = p0 + wn * 64 + nf * 16 + l15;
        size_t off = ((size_t)bg * Cn + c) * HWn + p;
        x2[off] = x[off] + acc[mf][nf][r];
      }
    }
}

// ------------------------------------------------------------ conv3x3 -----
// Implicit-GEMM 3x3 SAME conv, 128oc x 128p tile (2 rows x 64 cols).
// B: haloed LDS [4 rows][66 cols][40-pad ic], single bf16 plane; 9 taps =
// 9 shifted reads. A: pre-swizzled weight frags from global/L2 (1KB/frag).
// conv1: BN at staging (in-bounds only), GELU epilogue -> NHWC bf16 mid.
// conv2: NHWC bf16 input (16B contiguous staging), f32 residual epilogue.
template <int IN_C, int OUT_C, bool IN_NHWC, bool DO_BN, bool GELU_NHWC,
          bool DO_RESID, bool IN_ABS, bool OUT_ABS>
__global__ __launch_bounds__(256, 4) void conv_mfma(
    const void* __restrict__ in_v, const ushort* __restrict__ wth,
    const ushort* __restrict__ wtl, const float* __restrict__ bias,
    const float* __restrict__ inv2, const float* __restrict__ beta2,
    const float* __restrict__ resid, void* __restrict__ out_v, int b0) {
  constexpr int NOB = OUT_C / 16, NIB = IN_C / 32;
  const int tid = threadIdx.x, lane = tid & 63, wave = tid >> 6;
  const int wm = wave >> 1, wn = wave & 1;
  const int l15 = lane & 15, lg = lane >> 4;
  const int p0 = blockIdx.x * 128;
  const int y0 = p0 >> 6;  // two output rows y0, y0+1
  const int oc0 = blockIdx.y * 128;
  const int bz = blockIdx.z;
  const int bin = IN_ABS ? (b0 + bz) : bz;
  const int bout = OUT_ABS ? (b0 + bz) : bz;
  __shared__ __align__(16) ushort Xb[4 * 66 * GPAD];  // 21.1 KB
  f32x4 acc[4][4] = {};

  for (int ic0 = 0; ic0 < IN_C; ic0 += 32) {
    __syncthreads();
    for (int i = tid; i < 4 * 66 * 4; i += 256) {
      int c = i % 66;
      int rg = i / 66;
      int r = rg & 3, g = rg >> 2;
      int gy = y0 - 1 + r, gx = c - 1;
      bool inb = (gy >= 0 && gy < 64 && gx >= 0 && gx < 64);
      uint4 w = make_uint4(0u, 0u, 0u, 0u);
      if constexpr (IN_NHWC) {
        if (inb)
          w = *(const uint4*)((const ushort*)in_v +
                              (((size_t)bin * HWn + gy * 64 + gx) * IN_C + ic0 +
                               g * 8));
      } else {
        float v[8] = {};
        if (inb) {
          const float* src = (const float*)in_v +
                             ((size_t)bin * IN_C + ic0 + g * 8) * HWn +
                             gy * 64 + gx;
#pragma unroll
          for (int j = 0; j < 8; ++j) {
            float val = src[(size_t)j * HWn];
            if constexpr (DO_BN)
              val = val * inv2[ic0 + g * 8 + j] + beta2[ic0 + g * 8 + j];
            v[j] = val;
          }
        }
        w = pack8(v);
      }
      *(uint4*)&Xb[(r * 66 + c) * GPAD + g * 8] = w;
    }
    __syncthreads();

#pragma unroll
    for (int kh = 0; kh < 3; ++kh)
#pragma unroll
      for (int kw = 0; kw < 3; ++kw) {
        const int tap = kh * 3 + kw;
        bf16x8 Bf[4];
#pragma unroll
        for (int nf = 0; nf < 4; ++nf) {
          int n = wn * 64 + nf * 16 + l15;
          int addr = (((n >> 6) + kh) * 66 + (n & 63) + kw) * GPAD + lg * 8;
          Bf[nf] = *(const bf16x8*)&Xb[addr];
        }
#pragma unroll
        for (int mf = 0; mf < 4; ++mf) {
          size_t fidx =
              ((size_t)(tap * NOB + (oc0 >> 4) + wm * 4 + mf)) * NIB +
              (ic0 >> 5);
          bf16x8 Ah = *(const bf16x8*)(wth + fidx * 512 + lane * 8);
          bf16x8 Al = *(const bf16x8*)(wtl + fidx * 512 + lane * 8);
#pragma unroll
          for (int nf = 0; nf < 4; ++nf)
            acc[mf][nf] = MFMA(Al, Bf[nf], MFMA(Ah, Bf[nf], acc[mf][nf]));
        }
      }
  }

  if constexpr (GELU_NHWC) {
    // NHWC bf16 output: 4 consecutive oc (r=0..3) pack to one 8B store.
#pragma unroll
    for (int mf = 0; mf < 4; ++mf) {
      int ocb = oc0 + wm * 64 + mf * 16 + lg * 4;
#pragma unroll
      for (int nf = 0; nf < 4; ++nf) {
        int n = wn * 64 + nf * 16 + l15;
        size_t pos = (size_t)bout * HWn + p0 + n;
        ushort4 pk;
        float vv;
        vv = acc[mf][nf][0] + bias[ocb + 0];
        pk.x = (ushort)bf16r(0.5f * vv * (1.f + erff(vv * 0.70710678118654752f)));
        vv = acc[mf][nf][1] + bias[ocb + 1];
        pk.y = (ushort)bf16r(0.5f * vv * (1.f + erff(vv * 0.70710678118654752f)));
        vv = acc[mf][nf][2] + bias[ocb + 2];
        pk.z = (ushort)bf16r(0.5f * vv * (1.f + erff(vv * 0.70710678118654752f)));
        vv = acc[mf][nf][3] + bias[ocb + 3];
        pk.w = (ushort)bf16r(0.5f * vv * (1.f + erff(vv * 0.70710678118654752f)));
        *(ushort4*)((ushort*)out_v + pos * OUT_C + ocb) = pk;
      }
    }
  } else {
#pragma unroll
    for (int mf = 0; mf < 4; ++mf)
#pragma unroll
      for (int r = 0; r < 4; ++r) {
        int oc = oc0 + wm * 64 + mf * 16 + lg * 4 + r;
        float bv = bias[oc];
#pragma unroll
        for (int nf = 0; nf < 4; ++nf) {
          int n = wn * 64 + nf * 16 + l15;
          size_t off = ((size_t)bout * OUT_C + oc) * HWn + p0 + n;
          float vv = acc[mf][nf][r] + bv;
          if constexpr (DO_RESID) vv += resid[off];
          ((float*)out_v)[off] = vv;
        }
      }
  }
}

// ----------------------------------------------------------------------- //
extern "C" void kernel_launch(void* const* d_in, const int* in_sizes, int n_in,
                              void* d_out, int out_size, void* d_ws,
                              size_t ws_size, hipStream_t stream) {
  const float* x = (const float*)d_in[0];
  const float* bn1_g = (const float*)d_in[1];
  const float* bn1_b = (const float*)d_in[2];
  const float* bn1_m = (const float*)d_in[3];
  const float* bn1_v = (const float*)d_in[4];
  const float* kmat = (const float*)d_in[5];
  const float* vmat = (const float*)d_in[6];
  const float* bn2_g = (const float*)d_in[7];
  const float* bn2_b = (const float*)d_in[8];
  const float* bn2_m = (const float*)d_in[9];
  const float* bn2_v = (const float*)d_in[10];
  const float* w1 = (const float*)d_in[11];
  const float* b1 = (const float*)d_in[12];
  const float* w2 = (const float*)d_in[13];
  const float* b2 = (const float*)d_in[14];
  float* out = (float*)d_out;

  // ---- workspace carve (bytes; every chunk 512B-aligned) ----
  char* p = (char*)d_ws;
  float* keff = (float*)p;   p += (size_t)ICn * Cn * 4;
  float* biask = (float*)p;  p += 1024;
  float* inv2 = (float*)p;   p += 512;
  float* beta2 = (float*)p;  p += 512;
  ushort* k1h = (ushort*)p;  p += (size_t)ICn * Cn * 2;
  ushort* k1l = (ushort*)p;  p += (size_t)ICn * Cn * 2;
  ushort* vh = (ushort*)p;   p += (size_t)Cn * ICn * 2;
  ushort* vl = (ushort*)p;   p += (size_t)Cn * ICn * 2;
  ushort* wt1h = (ushort*)p; p += (size_t)9 * HIDn * Cn * 2;
  ushort* wt1l = (ushort*)p; p += (size_t)9 * HIDn * Cn * 2;
  ushort* wt2h = (ushort*)p; p += (size_t)9 * Cn * HIDn * 2;
  ushort* wt2l = (ushort*)p; p += (size_t)9 * Cn * HIDn * 2;
  size_t const_bytes = (size_t)(p - (char*)d_ws);

  // per-sample: S fp32 [256][4096] = 4MB; mid NHWC bf16 [4096][512] = 4MB.
  const size_t SM_BYTES = (size_t)ICn * HWn * 4;  // == HIDn*HWn*2
  const size_t HS_BYTES = (size_t)NHn * HWn * 4;
  int bc = 32;
  while (bc > 1 && const_bytes + (size_t)bc * (SM_BYTES + HS_BYTES) > ws_size)
    bc >>= 1;
  float* S = (float*)p;        // S dead before conv1 writes mid (same region)
  ushort* mid = (ushort*)p;    // NHWC bf16
  float* hsum = (float*)(p + (size_t)bc * SM_BYTES);
  float* x2 = out;  // x2 lives in d_out; conv2 finalizes in-place

  prep_a_kernel<<<dim3(1), dim3(256), 0, stream>>>(
      bn1_g, bn1_b, bn1_m, bn1_v, kmat, bn2_g, bn2_b, bn2_m, bn2_v, keff,
      biask, inv2, beta2);
  prep_b_kernel<<<dim3(1024), dim3(256), 0, stream>>>(
      keff, vmat, w1, w2, k1h, k1l, vh, vl, wt1h, wt1l, wt2h, wt2l);

  for (int b0 = 0; b0 < Bn; b0 += bc) {
    gemm1_mfma<<<dim3(32, 2, bc), dim3(256), 0, stream>>>(x, k1h, k1l, biask,
                                                          S, b0);
    softmax_kernel<<<dim3(bc * ICn), dim3(256), 0, stream>>>(S);
    hsum_kernel<<<dim3(4, NHn, bc), dim3(256), 0, stream>>>(S, hsum);
    gemm2_mfma<<<dim3(32, 1, bc), dim3(256), 0, stream>>>(S, vh, vl, hsum, x,
                                                          x2, b0);
    conv_mfma<Cn, HIDn, false, true, true, false, true, false>
        <<<dim3(32, 4, bc), dim3(256), 0, stream>>>(x2, wt1h, wt1l, b1, inv2,
                                                    beta2, nullptr, mid, b0);
    conv_mfma<HIDn, Cn, true, false, false, true, false, true>
        <<<dim3(32, 1, bc), dim3(256), 0, stream>>>(mid, wt2h, wt2l, b2,
                                                    nullptr, nullptr, x2, out,
                                                    b0);
  }
}